// Round 10
// baseline (5418.552 us; speedup 1.0000x reference)
//
#include <hip/hip_runtime.h>
#include <hip/hip_bf16.h>
#include <cstdint>
#include <cstddef>

#define T_STEPS 256
#define BATCH   128
#define VOCAB   256
#define EDIM    512
#define NH      1024
#define GDIM    4096   // 4*NH
#define NST0    40     // layer0 k-steps: 8 (x) + 32 (h)
#define NST1    64     // layer1 k-steps: 32 (h0) + 32 (h1)

typedef __attribute__((ext_vector_type(8))) short short8;
typedef __attribute__((ext_vector_type(4))) float floatx4;

__device__ __forceinline__ float sigmoidf_(float x) { return 1.0f / (1.0f + __expf(-x)); }
__device__ __forceinline__ float tanhf_(float x)    { return 1.0f - 2.0f / (__expf(2.0f * x) + 1.0f); }

typedef __attribute__((address_space(1))) const unsigned int guint;
typedef __attribute__((address_space(3))) unsigned int luint;
__device__ __forceinline__ void load_lds16(const void* g, void* l) {
    __builtin_amdgcn_global_load_lds((guint*)g, (luint*)l, 16, 0, 0);
}

// ---------------- fp32 GEMM (prep only: Wcomb = emb @ W0x) ----------------
#define BM 128
#define BN 128
#define BK 16
__global__ __launch_bounds__(256) void sgemm_f32(
    const float* __restrict__ A, const float* __restrict__ B,
    float* __restrict__ C, int M, int N, int K)
{
    __shared__ float As[BK][BM + 4];
    __shared__ float Bs[BK][BN + 4];
    const int tid = threadIdx.x;
    const int tr = tid >> 4, tc = tid & 15;
    const int bm = blockIdx.y, bn = blockIdx.x;
    const float* Ab = A + (size_t)bm * BM * K;
    float acc[8][8];
    #pragma unroll
    for (int i = 0; i < 8; ++i)
        #pragma unroll
        for (int j = 0; j < 8; ++j) acc[i][j] = 0.f;
    for (int k0 = 0; k0 < K; k0 += BK) {
        #pragma unroll
        for (int l = 0; l < 2; ++l) {
            int idx = tid + l * 256;
            int row = idx >> 2, c4 = idx & 3;
            float4 v = *(const float4*)(Ab + (size_t)row * K + k0 + c4 * 4);
            As[c4 * 4 + 0][row] = v.x; As[c4 * 4 + 1][row] = v.y;
            As[c4 * 4 + 2][row] = v.z; As[c4 * 4 + 3][row] = v.w;
        }
        #pragma unroll
        for (int l = 0; l < 2; ++l) {
            int idx = tid + l * 256;
            int row = idx >> 5, c4 = idx & 31;
            *(float4*)&Bs[row][c4 * 4] = *(const float4*)(B + (size_t)(k0 + row) * N + bn * BN + c4 * 4);
        }
        __syncthreads();
        #pragma unroll
        for (int kk = 0; kk < BK; ++kk) {
            float4 a0 = *(const float4*)&As[kk][tr * 8];
            float4 a1 = *(const float4*)&As[kk][tr * 8 + 4];
            float4 b0 = *(const float4*)&Bs[kk][tc * 8];
            float4 b1 = *(const float4*)&Bs[kk][tc * 8 + 4];
            float av[8] = {a0.x, a0.y, a0.z, a0.w, a1.x, a1.y, a1.z, a1.w};
            float bv[8] = {b0.x, b0.y, b0.z, b0.w, b1.x, b1.y, b1.z, b1.w};
            #pragma unroll
            for (int i = 0; i < 8; ++i)
                #pragma unroll
                for (int j = 0; j < 8; ++j) acc[i][j] += av[i] * bv[j];
        }
        __syncthreads();
    }
    #pragma unroll
    for (int i = 0; i < 8; ++i) {
        size_t row = (size_t)bm * BM + tr * 8 + i;
        #pragma unroll
        for (int j = 0; j < 8; j += 4) {
            int col = bn * BN + tc * 8 + j;
            *(float4*)(C + row * N + col) =
                make_float4(acc[i][j], acc[i][j+1], acc[i][j+2], acc[i][j+3]);
        }
    }
}

// ---------------- transpose + fp32->bf16 ----------------
__global__ __launch_bounds__(256) void transpose_to_bf16(
    const float* __restrict__ src, __hip_bfloat16* __restrict__ dst, int R, int C)
{
    __shared__ float t[32][33];
    int x = blockIdx.x * 32 + threadIdx.x;
    #pragma unroll
    for (int i = 0; i < 4; ++i) {
        int y = blockIdx.y * 32 + threadIdx.y + i * 8;
        t[threadIdx.y + i * 8][threadIdx.x] = src[(size_t)y * C + x];
    }
    __syncthreads();
    int x2 = blockIdx.y * 32 + threadIdx.x;
    #pragma unroll
    for (int i = 0; i < 4; ++i) {
        int y2 = blockIdx.x * 32 + threadIdx.y + i * 8;
        dst[(size_t)y2 * R + x2] = __float2bfloat16(t[threadIdx.x][threadIdx.y + i * 8]);
    }
}

// ------- pack weights: per-(block j, k-step s, n-tile t) 1KB fragments -------
// elem_off = ((((j*NSTEPS + s)*2 + t)*64 + quad*16 + l16)*8 + jj
__global__ __launch_bounds__(256) void pack_w2(
    const float* __restrict__ src, __hip_bfloat16* __restrict__ dst,
    int koff, int NSTEPS)
{
    __shared__ float t[64][33];
    const int tid = threadIdx.x;
    const int xt = blockIdx.x;
    const int kt = blockIdx.y;
    {
        int yl = tid >> 3;
        int x0 = (tid & 7) * 8;
        const float* p = src + (size_t)(kt * 32 + yl) * GDIM + xt * 64 + x0;
        float4 v0 = *(const float4*)p;
        float4 v1 = *(const float4*)(p + 4);
        t[x0 + 0][yl] = v0.x; t[x0 + 1][yl] = v0.y; t[x0 + 2][yl] = v0.z; t[x0 + 3][yl] = v0.w;
        t[x0 + 4][yl] = v1.x; t[x0 + 5][yl] = v1.y; t[x0 + 6][yl] = v1.z; t[x0 + 7][yl] = v1.w;
    }
    __syncthreads();
    {
        int ll = tid >> 2;
        int quad = tid & 3;
        int lincol = xt * 64 + ll;
        int g = lincol >> 10, n = lincol & 1023;
        int j = n >> 3, c = n & 7;
        int tt = g >> 1;
        int l16 = (g & 1) * 8 + c;
        int s = (koff >> 5) + kt;
        __hip_bfloat16 o[8];
        #pragma unroll
        for (int jj = 0; jj < 8; ++jj)
            o[jj] = __float2bfloat16(t[ll][quad * 8 + jj]);
        size_t off = ((((size_t)j * NSTEPS + s) * 2 + tt) * 64 + (size_t)quad * 16 + l16) * 8;
        *(uint4*)(dst + off) = *(const uint4*)o;
    }
}

// ---------------- fp32 -> bf16 convert ----------------
__global__ __launch_bounds__(256) void convert_to_bf16(
    const float* __restrict__ src, __hip_bfloat16* __restrict__ dst, size_t n4)
{
    size_t i = (size_t)blockIdx.x * 256 + threadIdx.x;
    if (i < n4) {
        float4 v = *(const float4*)(src + i * 4);
        __hip_bfloat16 o[4] = {__float2bfloat16(v.x), __float2bfloat16(v.y),
                               __float2bfloat16(v.z), __float2bfloat16(v.w)};
        *(uint2*)(dst + i * 4) = *(uint2*)o;
    }
}

// ---------------- bf16 MFMA GEMM (output layer) ----------------
#define GKP 40
__global__ __launch_bounds__(256) void gemm_bt(
    const __hip_bfloat16* __restrict__ A, const __hip_bfloat16* __restrict__ Bt,
    const float* __restrict__ bias, float* __restrict__ C, int M, int N, int K)
{
    __shared__ __hip_bfloat16 As[128 * GKP];
    __shared__ __hip_bfloat16 Bs[128 * GKP];
    const int tid = threadIdx.x;
    const int wave = tid >> 6, lane = tid & 63;
    const int quad = lane >> 4, l16 = lane & 15;
    const int wm = (wave >> 1) * 64, wn = (wave & 1) * 64;
    const size_t Arow0 = (size_t)blockIdx.y * 128;
    const size_t Brow0 = (size_t)blockIdx.x * 128;
    floatx4 acc[4][4];
    #pragma unroll
    for (int i = 0; i < 4; ++i)
        #pragma unroll
        for (int j = 0; j < 4; ++j) acc[i][j] = (floatx4)0.f;

    for (int k0 = 0; k0 < K; k0 += 32) {
        #pragma unroll
        for (int l = 0; l < 2; ++l) {
            int idx = tid + l * 256;
            int row = idx >> 2, seg = idx & 3;
            *(uint4*)(As + row * GKP + seg * 8) =
                *(const uint4*)(A + (Arow0 + row) * K + k0 + seg * 8);
            *(uint4*)(Bs + row * GKP + seg * 8) =
                *(const uint4*)(Bt + (Brow0 + row) * K + k0 + seg * 8);
        }
        __syncthreads();
        short8 af[4], bf[4];
        #pragma unroll
        for (int i = 0; i < 4; ++i)
            af[i] = *(const short8*)(As + (wm + i * 16 + l16) * GKP + quad * 8);
        #pragma unroll
        for (int j = 0; j < 4; ++j)
            bf[j] = *(const short8*)(Bs + (wn + j * 16 + l16) * GKP + quad * 8);
        #pragma unroll
        for (int i = 0; i < 4; ++i)
            #pragma unroll
            for (int j = 0; j < 4; ++j)
                acc[i][j] = __builtin_amdgcn_mfma_f32_16x16x32_bf16(af[i], bf[j], acc[i][j], 0, 0, 0);
        __syncthreads();
    }
    #pragma unroll
    for (int i = 0; i < 4; ++i)
        #pragma unroll
        for (int j = 0; j < 4; ++j) {
            int col = (int)Brow0 + wn + j * 16 + l16;
            float bv = bias ? bias[col] : 0.f;
            #pragma unroll
            for (int r = 0; r < 4; ++r) {
                size_t row = Arow0 + wm + i * 16 + quad * 4 + r;
                C[row * N + col] = acc[i][j][r] + bv;
            }
        }
}

// ---- fallback helper: single-panel segment, depth-3 prefetch, 8-col fmt ----
template<int NC, int W>
__device__ __forceinline__ void seg_run(
    const __hip_bfloat16* __restrict__ pA,
    const __hip_bfloat16* Wlds, int lane,
    floatx4& acc0, floatx4& acc1)
{
    constexpr int D = (NC < 3) ? NC : 3;
    short8 af[3][8];
    #pragma unroll
    for (int c = 0; c < D; ++c)
        #pragma unroll
        for (int ss = 0; ss < 8; ++ss)
            af[c][ss] = *(const short8*)(pA + (size_t)c * 256 + ss * 32);
    #pragma unroll
    for (int c = 0; c < NC; ++c) {
        #pragma unroll
        for (int ss = 0; ss < 8; ++ss) {
            const int s = (W + c) * 8 + ss;
            short8 bf0 = *(const short8*)&Wlds[s * 1024 + lane * 8];
            short8 bf1 = *(const short8*)&Wlds[s * 1024 + 512 + lane * 8];
            acc0 = __builtin_amdgcn_mfma_f32_16x16x32_bf16(af[c % 3][ss], bf0, acc0, 0, 0, 0);
            acc1 = __builtin_amdgcn_mfma_f32_16x16x32_bf16(af[c % 3][ss], bf1, acc1, 0, 0, 0);
        }
        if (c + 3 < NC) {
            #pragma unroll
            for (int ss = 0; ss < 8; ++ss)
                af[(c + 3) % 3][ss] = *(const short8*)(pA + (size_t)(c + 3) * 256 + ss * 32);
        }
    }
}

// ---------------- diagonal fused LSTM step (fallback path) ----------------
__global__ __launch_bounds__(512) void lstm_diag(
    const __hip_bfloat16* __restrict__ inbf,
    const __hip_bfloat16* __restrict__ Wpack0,
    const __hip_bfloat16* __restrict__ Wpack1,
    const float* __restrict__ b0, const float* __restrict__ b1,
    __hip_bfloat16* __restrict__ h0_cur,
    const __hip_bfloat16* __restrict__ h0_prev,
    float* __restrict__ c0, float* __restrict__ c1,
    __hip_bfloat16* __restrict__ H1all,
    int d)
{
    const int bid = blockIdx.x;
    const int layer = (bid >> 3) & 1;
    const int j = ((bid >> 4) << 3) | (bid & 7);
    if (layer == 0 && d >= T_STEPS) return;
    if (layer == 1 && d == 0) return;

    __shared__ __attribute__((aligned(16))) __hip_bfloat16 Wlds[65536];

    const int tid = threadIdx.x;
    const int wave = tid >> 6, lane = tid & 63;
    const int quad = lane >> 4, l16 = lane & 15;

    const __hip_bfloat16 *A0, *A1;
    int A0stride;
    const float* bb; float* cst; __hip_bfloat16* hout;
    bool first;
    if (layer == 0) {
        first = (d == 0);
        bb = b0; cst = c0;
        A0 = inbf + (size_t)d * (BATCH * VOCAB); A0stride = VOCAB;
        A1 = h0_prev;
        hout = h0_cur;
        const __hip_bfloat16* Wp = Wpack0 + (size_t)j * (NST0 * 1024);
        #pragma unroll
        for (int it = 0; it < 10; ++it)
            load_lds16(Wp + it * 4096 + tid * 8, Wlds + it * 4096 + tid * 8);
    } else {
        first = (d == 1);
        bb = b1; cst = c1;
        A0 = h0_prev; A0stride = NH;
        A1 = (d >= 2) ? (H1all + (size_t)(d - 2) * (BATCH * NH)) : h0_prev;
        hout = H1all + (size_t)(d - 1) * (BATCH * NH);
        const __hip_bfloat16* Wp = Wpack1 + (size_t)j * (NST1 * 1024);
        #pragma unroll
        for (int it = 0; it < 16; ++it)
            load_lds16(Wp + it * 4096 + tid * 8, Wlds + it * 4096 + tid * 8);
    }

    const int row = wave * 16 + l16;
    const __hip_bfloat16* pA0 = A0 + (size_t)row * A0stride + quad * 8;
    const __hip_bfloat16* pA1 = A1 + (size_t)row * NH + quad * 8;

    const int cc = j * 8 + (l16 & 7);
    float bv0 = bb[((l16 < 8) ? 0 : 1) * NH + cc];
    float bv1 = bb[((l16 < 8) ? 2 : 3) * NH + cc];
    float cold[4];
    {
        const int bbase = 16 * wave + quad * 4;
        #pragma unroll
        for (int r = 0; r < 4; ++r)
            cold[r] = first ? 0.f : cst[(size_t)(bbase + r) * NH + cc];
    }
    floatx4 acc0 = {bv0, bv0, bv0, bv0};
    floatx4 acc1 = {bv1, bv1, bv1, bv1};

    __syncthreads();
    if (layer == 0) {
        seg_run<1, 0>(pA0, Wlds, lane, acc0, acc1);
        if (!first) seg_run<4, 1>(pA1, Wlds, lane, acc0, acc1);
    } else {
        if (first) {
            seg_run<4, 0>(pA0, Wlds, lane, acc0, acc1);
        } else {
            seg_run<4, 4>(pA1, Wlds, lane, acc0, acc1);
            seg_run<4, 0>(pA0, Wlds, lane, acc0, acc1);
        }
    }

    #pragma unroll
    for (int r = 0; r < 4; ++r) {
        float a0 = acc0[r], a1 = acc1[r];
        float p0 = __shfl_xor(a0, 8, 64);
        float p1 = __shfl_xor(a1, 8, 64);
        if (l16 < 8) {
            int b = 16 * wave + quad * 4 + r;
            float f  = sigmoidf_(a0);
            float ig = sigmoidf_(p0);
            float oo = sigmoidf_(a1);
            float gg = tanhf_(p1);
            size_t idx = (size_t)b * NH + cc;
            float cn = f * cold[r] + ig * gg;
            float hn = oo * tanhf_(cn);
            cst[idx] = cn;
            hout[idx] = __float2bfloat16(hn);
        }
    }
}

// ---------------- distributed epoch sync ----------------
// Per-WAVE spin: every wave independently polls all 128 peer slots with 2
// coalesced agent-scope lane-loads + __all. No fences, no RMW, no barrier.
__device__ __forceinline__ void spin_wave(const uint32_t* ep, uint32_t target, int lane) {
    asm volatile("" ::: "memory");
    for (;;) {
        uint32_t a = __hip_atomic_load(&ep[lane], __ATOMIC_RELAXED, __HIP_MEMORY_SCOPE_AGENT);
        uint32_t b = __hip_atomic_load(&ep[lane + 64], __ATOMIC_RELAXED, __HIP_MEMORY_SCOPE_AGENT);
        if (__all(a >= target && b >= target)) break;
        __builtin_amdgcn_s_sleep(1);
    }
    asm volatile("" ::: "memory");
}

__device__ __forceinline__ void arrive_ep(uint32_t* slot, uint32_t val) {
    __syncthreads();   // each wave drains vmcnt: sc1 h-stores device-visible
    asm volatile("" ::: "memory");
    if (threadIdx.x == 0)
        __hip_atomic_store(slot, val, __ATOMIC_RELAXED, __HIP_MEMORY_SCOPE_AGENT);
}

__global__ void zero_bar(uint32_t* p) { p[threadIdx.x] = 0; }

// ---- epilogue: gates, c-reg update, pack 8 cols -> 2x8B sc1 stores ----
__device__ __forceinline__ void epilogue_store(
    floatx4 acc0, floatx4 acc1, float* creg, bool first,
    int wave, int quad, int l16, int cc8base,
    __hip_bfloat16* __restrict__ hout)
{
    #pragma unroll
    for (int r = 0; r < 4; ++r) {
        float a0 = acc0[r], a1 = acc1[r];
        float p0 = __shfl_xor(a0, 8, 64);
        float p1 = __shfl_xor(a1, 8, 64);
        float f  = sigmoidf_(a0);
        float ig = sigmoidf_(p0);
        float oo = sigmoidf_(a1);
        float gg = tanhf_(p1);
        float cn = f * (first ? 0.f : creg[r]) + ig * gg;
        if (l16 < 8) creg[r] = cn;
        float hn = oo * tanhf_(cn);
        union { __hip_bfloat16 h; unsigned short u; } cv;
        cv.h = __float2bfloat16(hn);
        unsigned int v1 = (unsigned int)cv.u |
                          (__shfl_xor((unsigned int)cv.u, 1, 64) << 16);
        unsigned int v2 = __shfl_xor(v1, 2, 64);
        unsigned long long p8 = (unsigned long long)v1 |
                                ((unsigned long long)v2 << 32);
        if (l16 == 0 || l16 == 4) {
            int b = 16 * wave + quad * 4 + r;
            __hip_atomic_store((unsigned long long*)&hout[(size_t)b * NH + cc8base + l16],
                               p8, __ATOMIC_RELAXED, __HIP_MEMORY_SCOPE_AGENT);
        }
    }
}

// ---------------- persistent LSTM v7: K-split waves, weights in REGISTERS ----
// 256 blocks (1/CU). Block j owns 8 cols of ONE layer (layer=(bid>>3)&1).
// Wave w holds its K-slice's B-fragments in VGPRs for all 257 steps
// (L0: 5 ksteps = 40 VGPRs; L1: 8 ksteps = 64 VGPRs). ZERO LDS weight reads.
// Each wave computes partials for ALL 128 batch rows over its K-slice;
// partials are reduced through a 128KB LDS buffer (1 barrier), then the
// standard epilogue (identical thread mapping -> creg/pack logic unchanged).
// Dependencies are per-wave: L1's h1-slices need only ep1, h0-slices only
// ep0 -> automatic compute/wait overlap without manual phasing.
__global__ __launch_bounds__(512, 2) void lstm_persist7(
    const __hip_bfloat16* __restrict__ inbf,
    const __hip_bfloat16* __restrict__ Wpack0,
    const __hip_bfloat16* __restrict__ Wpack1,
    const float* __restrict__ b0, const float* __restrict__ b1,
    __hip_bfloat16* __restrict__ H0all,        // [256][128][1024]
    __hip_bfloat16* __restrict__ H1all,        // [256][128][1024]
    uint32_t* __restrict__ bar)                // [0..127]=ep0, [128..255]=ep1
{
    __shared__ __attribute__((aligned(16))) float red[32768];   // 128 KB

    const int bid = blockIdx.x;
    const int layer = (bid >> 3) & 1;
    const int j = ((bid >> 4) << 3) | (bid & 7);
    const int tid = threadIdx.x;
    const int wv = tid >> 6, lane = tid & 63;
    const int quad = lane >> 4, l16 = lane & 15;

    uint32_t* ep0 = bar;
    uint32_t* ep1 = bar + 128;

    // ---- one-time: this wave's B-fragments -> registers ----
    // L0 wave w: breg[0]=x-kstep w; breg[1..4]=h-ksteps 8+4w..8+4w+3.
    // L1 wave w: breg[0..3]=h1-ksteps 32+4w..; breg[4..7]=h0-ksteps 4w..4w+3.
    short8 breg[8][2];
    if (layer == 0) {
        const __hip_bfloat16* Wp = Wpack0 + (size_t)j * (NST0 * 1024);
        #pragma unroll
        for (int t = 0; t < 2; ++t)
            breg[0][t] = *(const short8*)(Wp + ((size_t)wv * 2 + t) * 512 + lane * 8);
        #pragma unroll
        for (int i = 0; i < 4; ++i) {
            const int ks = 8 + 4 * wv + i;
            #pragma unroll
            for (int t = 0; t < 2; ++t)
                breg[1 + i][t] = *(const short8*)(Wp + ((size_t)ks * 2 + t) * 512 + lane * 8);
        }
        #pragma unroll
        for (int i = 5; i < 8; ++i) {
            breg[i][0] = breg[0][0];   // unused, keep defined
            breg[i][1] = breg[0][1];
        }
    } else {
        const __hip_bfloat16* Wp = Wpack1 + (size_t)j * (NST1 * 1024);
        #pragma unroll
        for (int i = 0; i < 4; ++i) {
            const int ks1 = 32 + 4 * wv + i;      // h1 slice
            const int ks0 = 4 * wv + i;           // h0 slice
            #pragma unroll
            for (int t = 0; t < 2; ++t) {
                breg[i][t]     = *(const short8*)(Wp + ((size_t)ks1 * 2 + t) * 512 + lane * 8);
                breg[4 + i][t] = *(const short8*)(Wp + ((size_t)ks0 * 2 + t) * 512 + lane * 8);
            }
        }
    }

    const int cc = j * 8 + (l16 & 7);
    const float* bb = layer ? b1 : b0;
    const float bv0 = bb[((l16 < 8) ? 0 : 1) * NH + cc];
    const float bv1 = bb[((l16 < 8) ? 2 : 3) * NH + cc];
    float creg[4] = {0.f, 0.f, 0.f, 0.f};

    // A-fragment column base for this wave's slices (elements)
    const int hcol = 4 * wv * 32 + quad * 8;      // h-slice base (L0 h / L1 both)
    const int xcol = wv * 32 + quad * 8;          // L0 x-slice base

    const int dlo = layer ? 1 : 0;
    const int dhi = layer ? T_STEPS : (T_STEPS - 1);

    for (int d = dlo; d <= dhi; ++d) {
        const bool first = (d == dlo);
        floatx4 acc[8][2];
        #pragma unroll
        for (int m = 0; m < 8; ++m) {
            acc[m][0] = (floatx4)0.f;
            acc[m][1] = (floatx4)0.f;
        }

        __hip_bfloat16* hout;
        if (layer == 0) {
            // ---- x slice (no dependency) ----
            const __hip_bfloat16* pX = inbf + (size_t)d * (BATCH * VOCAB);
            {
                short8 af[8];
                #pragma unroll
                for (int m = 0; m < 8; ++m)
                    af[m] = *(const short8*)(pX + (size_t)(m * 16 + l16) * VOCAB + xcol);
                #pragma unroll
                for (int m = 0; m < 8; ++m) {
                    acc[m][0] = __builtin_amdgcn_mfma_f32_16x16x32_bf16(af[m], breg[0][0], acc[m][0], 0, 0, 0);
                    acc[m][1] = __builtin_amdgcn_mfma_f32_16x16x32_bf16(af[m], breg[0][1], acc[m][1], 0, 0, 0);
                }
            }
            if (!first) {
                spin_wave(ep0, (uint32_t)d, lane);
                const __hip_bfloat16* pH0 = H0all + (size_t)(d - 1) * (BATCH * NH);
                #pragma unroll
                for (int i = 0; i < 4; ++i) {
                    short8 af[8];
                    #pragma unroll
                    for (int m = 0; m < 8; ++m)
                        af[m] = *(const short8*)(pH0 + (size_t)(m * 16 + l16) * NH + hcol + i * 32);
                    #pragma unroll
                    for (int m = 0; m < 8; ++m) {
                        acc[m][0] = __builtin_amdgcn_mfma_f32_16x16x32_bf16(af[m], breg[1 + i][0], acc[m][0], 0, 0, 0);
                        acc[m][1] = __builtin_amdgcn_mfma_f32_16x16x32_bf16(af[m], breg[1 + i][1], acc[m][1], 0, 0, 0);
                    }
                }
            }
            hout = H0all + (size_t)d * (BATCH * NH);
        } else {
            if (!first) {
                // ---- h1 slice (needs only ep1: own layer's prior step) ----
                spin_wave(ep1, (uint32_t)(d - 1), lane);
                const __hip_bfloat16* pH1 = H1all + (size_t)(d - 2) * (BATCH * NH);
                #pragma unroll
                for (int i = 0; i < 4; ++i) {
                    short8 af[8];
                    #pragma unroll
                    for (int m = 0; m < 8; ++m)
                        af[m] = *(const short8*)(pH1 + (size_t)(m * 16 + l16) * NH + hcol + i * 32);
                    #pragma unroll
                    for (int m = 0; m < 8; ++m) {
                        acc[m][0] = __builtin_amdgcn_mfma_f32_16x16x32_bf16(af[m], breg[i][0], acc[m][0], 0, 0, 0);
                        acc[m][1] = __builtin_amdgcn_mfma_f32_16x16x32_bf16(af[m], breg[i][1], acc[m][1], 0, 0, 0);
                    }
                }
            }
            // ---- h0 slice (cross-layer dependency) ----
            spin_wave(ep0, (uint32_t)d, lane);
            const __hip_bfloat16* pH0 = H0all + (size_t)(d - 1) * (BATCH * NH);
            #pragma unroll
            for (int i = 0; i < 4; ++i) {
                short8 af[8];
                #pragma unroll
                for (int m = 0; m < 8; ++m)
                    af[m] = *(const short8*)(pH0 + (size_t)(m * 16 + l16) * NH + hcol + i * 32);
                #pragma unroll
                for (int m = 0; m < 8; ++m) {
                    acc[m][0] = __builtin_amdgcn_mfma_f32_16x16x32_bf16(af[m], breg[4 + i][0], acc[m][0], 0, 0, 0);
                    acc[m][1] = __builtin_amdgcn_mfma_f32_16x16x32_bf16(af[m], breg[4 + i][1], acc[m][1], 0, 0, 0);
                }
            }
            hout = H1all + (size_t)(d - 1) * (BATCH * NH);
        }

        // ---- write partials: cell idx = ((wv*2+t)*8+m)*64 + l16*4 + quad ----
        #pragma unroll
        for (int m = 0; m < 8; ++m) {
            *(floatx4*)&red[((((wv * 2 + 0) * 8 + m) * 64) + l16 * 4 + quad) * 4] = acc[m][0];
            *(floatx4*)&red[((((wv * 2 + 1) * 8 + m) * 64) + l16 * 4 + quad) * 4] = acc[m][1];
        }
        __syncthreads();

        // ---- sum 8 partials for this wave's 16 rows (m-tile == wv) ----
        floatx4 s0 = (floatx4)0.f, s1 = (floatx4)0.f;
        #pragma unroll
        for (int w = 0; w < 8; ++w) {
            s0 += *(const floatx4*)&red[((((w * 2 + 0) * 8 + wv) * 64) + l16 * 4 + quad) * 4];
            s1 += *(const floatx4*)&red[((((w * 2 + 1) * 8 + wv) * 64) + l16 * 4 + quad) * 4];
        }
        s0 += bv0;
        s1 += bv1;

        epilogue_store(s0, s1, creg, first, wv, quad, l16, j * 8, hout);

        // arrive: syncthreads (drains sc1 h-stores; also protects red reuse)
        arrive_ep(layer ? &ep1[j] : &ep0[j], (uint32_t)(layer ? d : d + 1));
    }
}

extern "C" void kernel_launch(void* const* d_in, const int* in_sizes, int n_in,
                              void* d_out, int out_size, void* d_ws, size_t ws_size,
                              hipStream_t stream)
{
    const float* inputs = (const float*)d_in[0];  // [256,128,256]
    const float* emb    = (const float*)d_in[1];  // [256,512]
    const float* w0     = (const float*)d_in[2];  // [1536,4096]
    const float* b0     = (const float*)d_in[3];  // [4096]
    const float* w1     = (const float*)d_in[4];  // [2048,4096]
    const float* b1     = (const float*)d_in[5];  // [4096]
    const float* outw   = (const float*)d_in[6];  // [1024,256]
    const float* outb   = (const float*)d_in[7];  // [256]
    float* out = (float*)d_out;                   // [32768,256]

    char* ws = (char*)d_ws;
    size_t off = 0;
    auto take = [&](size_t bytes) { char* p = ws + off; off += (bytes + 255) & ~(size_t)255; return p; };
    float* Wcomb = (float*)take((size_t)VOCAB * GDIM * 4);                          // 4 MB
    __hip_bfloat16* Wpack0 = (__hip_bfloat16*)take((size_t)128 * NST0 * 1024 * 2);  // 10 MB
    __hip_bfloat16* Wpack1 = (__hip_bfloat16*)take((size_t)128 * NST1 * 1024 * 2);  // 16 MB
    __hip_bfloat16* outwt  = (__hip_bfloat16*)take((size_t)NH * VOCAB * 2);         // 0.5 MB
    __hip_bfloat16* inbf   = (__hip_bfloat16*)take((size_t)T_STEPS * BATCH * VOCAB * 2); // 16 MB
    __hip_bfloat16* h0pp0  = (__hip_bfloat16*)take((size_t)BATCH * NH * 2);
    __hip_bfloat16* h0pp1  = (__hip_bfloat16*)take((size_t)BATCH * NH * 2);
    float* c0 = (float*)take((size_t)BATCH * NH * 4);
    float* c1 = (float*)take((size_t)BATCH * NH * 4);
    uint32_t* bar = (uint32_t*)take(1024);
    __hip_bfloat16* H1all  = (__hip_bfloat16*)take((size_t)T_STEPS * BATCH * NH * 2); // 64 MB
    __hip_bfloat16* H0all  = (__hip_bfloat16*)take((size_t)T_STEPS * BATCH * NH * 2); // 64 MB
    const bool ws_ok = (off <= ws_size);

    // ---- prep ----
    sgemm_f32<<<dim3(GDIM / BN, VOCAB / BM), 256, 0, stream>>>(
        emb, w0, Wcomb, VOCAB, GDIM, EDIM);
    pack_w2<<<dim3(64, VOCAB / 32), 256, 0, stream>>>(Wcomb, Wpack0, 0, NST0);
    pack_w2<<<dim3(64, NH / 32), 256, 0, stream>>>(w0 + (size_t)EDIM * GDIM, Wpack0, VOCAB, NST0);
    pack_w2<<<dim3(64, NH / 32), 256, 0, stream>>>(w1, Wpack1, 0, NST1);
    pack_w2<<<dim3(64, NH / 32), 256, 0, stream>>>(w1 + (size_t)NH * GDIM, Wpack1, NH, NST1);
    transpose_to_bf16<<<dim3(VOCAB / 32, NH / 32), dim3(32, 8), 0, stream>>>(
        outw, outwt, NH, VOCAB);
    {
        size_t n4 = (size_t)T_STEPS * BATCH * VOCAB / 4;
        convert_to_bf16<<<(int)((n4 + 255) / 256), 256, 0, stream>>>(inputs, inbf, n4);
    }
    zero_bar<<<1, 256, 0, stream>>>(bar);

    // ---- recurrence ----
    bool done = false;
    if (ws_ok) {
        void* args[] = { (void*)&inbf, (void*)&Wpack0, (void*)&Wpack1,
                         (void*)&b0, (void*)&b1,
                         (void*)&H0all, (void*)&H1all, (void*)&bar };
        hipError_t ce = hipLaunchCooperativeKernel(lstm_persist7, dim3(256), dim3(512),
                                                   args, 0u, stream);
        done = (ce == hipSuccess);
    }
    if (!done) {
        for (int d = 0; d <= T_STEPS; ++d) {
            __hip_bfloat16* hcur = (d & 1) ? h0pp1 : h0pp0;
            __hip_bfloat16* hprev = (d & 1) ? h0pp0 : h0pp1;
            lstm_diag<<<256, 512, 0, stream>>>(
                inbf, Wpack0, Wpack1, b0, b1, hcur, hprev, c0, c1, H1all, d);
        }
    }

    // ---- logits = H1 @ out_w + out_b ----
    gemm_bt<<<dim3(VOCAB / 128, (T_STEPS * BATCH) / 128), 256, 0, stream>>>(
        H1all, outwt, outb, out, T_STEPS * BATCH, VOCAB, NH);
}

// Round 11
// 4943.986 us; speedup vs baseline: 1.0960x; 1.0960x over previous
//
#include <hip/hip_runtime.h>
#include <hip/hip_bf16.h>
#include <cstdint>
#include <cstddef>

#define T_STEPS 256
#define BATCH   128
#define VOCAB   256
#define EDIM    512
#define NH      1024
#define GDIM    4096   // 4*NH
#define NST0    40     // layer0 k-steps: 8 (x) + 32 (h)
#define NST1    64     // layer1 k-steps: 32 (h0) + 32 (h1)

typedef __attribute__((ext_vector_type(8))) short short8;
typedef __attribute__((ext_vector_type(4))) float floatx4;

__device__ __forceinline__ float sigmoidf_(float x) { return 1.0f / (1.0f + __expf(-x)); }
__device__ __forceinline__ float tanhf_(float x)    { return 1.0f - 2.0f / (__expf(2.0f * x) + 1.0f); }

typedef __attribute__((address_space(1))) const unsigned int guint;
typedef __attribute__((address_space(3))) unsigned int luint;
__device__ __forceinline__ void load_lds16(const void* g, void* l) {
    __builtin_amdgcn_global_load_lds((guint*)g, (luint*)l, 16, 0, 0);
}

// ---------------- fp32 GEMM (prep only: Wcomb = emb @ W0x) ----------------
#define BM 128
#define BN 128
#define BK 16
__global__ __launch_bounds__(256) void sgemm_f32(
    const float* __restrict__ A, const float* __restrict__ B,
    float* __restrict__ C, int M, int N, int K)
{
    __shared__ float As[BK][BM + 4];
    __shared__ float Bs[BK][BN + 4];
    const int tid = threadIdx.x;
    const int tr = tid >> 4, tc = tid & 15;
    const int bm = blockIdx.y, bn = blockIdx.x;
    const float* Ab = A + (size_t)bm * BM * K;
    float acc[8][8];
    #pragma unroll
    for (int i = 0; i < 8; ++i)
        #pragma unroll
        for (int j = 0; j < 8; ++j) acc[i][j] = 0.f;
    for (int k0 = 0; k0 < K; k0 += BK) {
        #pragma unroll
        for (int l = 0; l < 2; ++l) {
            int idx = tid + l * 256;
            int row = idx >> 2, c4 = idx & 3;
            float4 v = *(const float4*)(Ab + (size_t)row * K + k0 + c4 * 4);
            As[c4 * 4 + 0][row] = v.x; As[c4 * 4 + 1][row] = v.y;
            As[c4 * 4 + 2][row] = v.z; As[c4 * 4 + 3][row] = v.w;
        }
        #pragma unroll
        for (int l = 0; l < 2; ++l) {
            int idx = tid + l * 256;
            int row = idx >> 5, c4 = idx & 31;
            *(float4*)&Bs[row][c4 * 4] = *(const float4*)(B + (size_t)(k0 + row) * N + bn * BN + c4 * 4);
        }
        __syncthreads();
        #pragma unroll
        for (int kk = 0; kk < BK; ++kk) {
            float4 a0 = *(const float4*)&As[kk][tr * 8];
            float4 a1 = *(const float4*)&As[kk][tr * 8 + 4];
            float4 b0 = *(const float4*)&Bs[kk][tc * 8];
            float4 b1 = *(const float4*)&Bs[kk][tc * 8 + 4];
            float av[8] = {a0.x, a0.y, a0.z, a0.w, a1.x, a1.y, a1.z, a1.w};
            float bv[8] = {b0.x, b0.y, b0.z, b0.w, b1.x, b1.y, b1.z, b1.w};
            #pragma unroll
            for (int i = 0; i < 8; ++i)
                #pragma unroll
                for (int j = 0; j < 8; ++j) acc[i][j] += av[i] * bv[j];
        }
        __syncthreads();
    }
    #pragma unroll
    for (int i = 0; i < 8; ++i) {
        size_t row = (size_t)bm * BM + tr * 8 + i;
        #pragma unroll
        for (int j = 0; j < 8; j += 4) {
            int col = bn * BN + tc * 8 + j;
            *(float4*)(C + row * N + col) =
                make_float4(acc[i][j], acc[i][j+1], acc[i][j+2], acc[i][j+3]);
        }
    }
}

// ---------------- transpose + fp32->bf16 ----------------
__global__ __launch_bounds__(256) void transpose_to_bf16(
    const float* __restrict__ src, __hip_bfloat16* __restrict__ dst, int R, int C)
{
    __shared__ float t[32][33];
    int x = blockIdx.x * 32 + threadIdx.x;
    #pragma unroll
    for (int i = 0; i < 4; ++i) {
        int y = blockIdx.y * 32 + threadIdx.y + i * 8;
        t[threadIdx.y + i * 8][threadIdx.x] = src[(size_t)y * C + x];
    }
    __syncthreads();
    int x2 = blockIdx.y * 32 + threadIdx.x;
    #pragma unroll
    for (int i = 0; i < 4; ++i) {
        int y2 = blockIdx.x * 32 + threadIdx.y + i * 8;
        dst[(size_t)y2 * R + x2] = __float2bfloat16(t[threadIdx.x][threadIdx.y + i * 8]);
    }
}

// ------- pack weights: per-(block j, k-step s, n-tile t) 1KB fragments -------
// elem_off = ((((j*NSTEPS + s)*2 + t)*64 + quad*16 + l16)*8 + jj
__global__ __launch_bounds__(256) void pack_w2(
    const float* __restrict__ src, __hip_bfloat16* __restrict__ dst,
    int koff, int NSTEPS)
{
    __shared__ float t[64][33];
    const int tid = threadIdx.x;
    const int xt = blockIdx.x;
    const int kt = blockIdx.y;
    {
        int yl = tid >> 3;
        int x0 = (tid & 7) * 8;
        const float* p = src + (size_t)(kt * 32 + yl) * GDIM + xt * 64 + x0;
        float4 v0 = *(const float4*)p;
        float4 v1 = *(const float4*)(p + 4);
        t[x0 + 0][yl] = v0.x; t[x0 + 1][yl] = v0.y; t[x0 + 2][yl] = v0.z; t[x0 + 3][yl] = v0.w;
        t[x0 + 4][yl] = v1.x; t[x0 + 5][yl] = v1.y; t[x0 + 6][yl] = v1.z; t[x0 + 7][yl] = v1.w;
    }
    __syncthreads();
    {
        int ll = tid >> 2;
        int quad = tid & 3;
        int lincol = xt * 64 + ll;
        int g = lincol >> 10, n = lincol & 1023;
        int j = n >> 3, c = n & 7;
        int tt = g >> 1;
        int l16 = (g & 1) * 8 + c;
        int s = (koff >> 5) + kt;
        __hip_bfloat16 o[8];
        #pragma unroll
        for (int jj = 0; jj < 8; ++jj)
            o[jj] = __float2bfloat16(t[ll][quad * 8 + jj]);
        size_t off = ((((size_t)j * NSTEPS + s) * 2 + tt) * 64 + (size_t)quad * 16 + l16) * 8;
        *(uint4*)(dst + off) = *(const uint4*)o;
    }
}

// ---------------- fp32 -> bf16 convert ----------------
__global__ __launch_bounds__(256) void convert_to_bf16(
    const float* __restrict__ src, __hip_bfloat16* __restrict__ dst, size_t n4)
{
    size_t i = (size_t)blockIdx.x * 256 + threadIdx.x;
    if (i < n4) {
        float4 v = *(const float4*)(src + i * 4);
        __hip_bfloat16 o[4] = {__float2bfloat16(v.x), __float2bfloat16(v.y),
                               __float2bfloat16(v.z), __float2bfloat16(v.w)};
        *(uint2*)(dst + i * 4) = *(uint2*)o;
    }
}

// ---------------- bf16 MFMA GEMM (output layer) ----------------
#define GKP 40
__global__ __launch_bounds__(256) void gemm_bt(
    const __hip_bfloat16* __restrict__ A, const __hip_bfloat16* __restrict__ Bt,
    const float* __restrict__ bias, float* __restrict__ C, int M, int N, int K)
{
    __shared__ __hip_bfloat16 As[128 * GKP];
    __shared__ __hip_bfloat16 Bs[128 * GKP];
    const int tid = threadIdx.x;
    const int wave = tid >> 6, lane = tid & 63;
    const int quad = lane >> 4, l16 = lane & 15;
    const int wm = (wave >> 1) * 64, wn = (wave & 1) * 64;
    const size_t Arow0 = (size_t)blockIdx.y * 128;
    const size_t Brow0 = (size_t)blockIdx.x * 128;
    floatx4 acc[4][4];
    #pragma unroll
    for (int i = 0; i < 4; ++i)
        #pragma unroll
        for (int j = 0; j < 4; ++j) acc[i][j] = (floatx4)0.f;

    for (int k0 = 0; k0 < K; k0 += 32) {
        #pragma unroll
        for (int l = 0; l < 2; ++l) {
            int idx = tid + l * 256;
            int row = idx >> 2, seg = idx & 3;
            *(uint4*)(As + row * GKP + seg * 8) =
                *(const uint4*)(A + (Arow0 + row) * K + k0 + seg * 8);
            *(uint4*)(Bs + row * GKP + seg * 8) =
                *(const uint4*)(Bt + (Brow0 + row) * K + k0 + seg * 8);
        }
        __syncthreads();
        short8 af[4], bf[4];
        #pragma unroll
        for (int i = 0; i < 4; ++i)
            af[i] = *(const short8*)(As + (wm + i * 16 + l16) * GKP + quad * 8);
        #pragma unroll
        for (int j = 0; j < 4; ++j)
            bf[j] = *(const short8*)(Bs + (wn + j * 16 + l16) * GKP + quad * 8);
        #pragma unroll
        for (int i = 0; i < 4; ++i)
            #pragma unroll
            for (int j = 0; j < 4; ++j)
                acc[i][j] = __builtin_amdgcn_mfma_f32_16x16x32_bf16(af[i], bf[j], acc[i][j], 0, 0, 0);
        __syncthreads();
    }
    #pragma unroll
    for (int i = 0; i < 4; ++i)
        #pragma unroll
        for (int j = 0; j < 4; ++j) {
            int col = (int)Brow0 + wn + j * 16 + l16;
            float bv = bias ? bias[col] : 0.f;
            #pragma unroll
            for (int r = 0; r < 4; ++r) {
                size_t row = Arow0 + wm + i * 16 + quad * 4 + r;
                C[row * N + col] = acc[i][j][r] + bv;
            }
        }
}

// ---- fallback helper: single-panel segment, depth-3 prefetch, 8-col fmt ----
template<int NC, int W>
__device__ __forceinline__ void seg_run(
    const __hip_bfloat16* __restrict__ pA,
    const __hip_bfloat16* Wlds, int lane,
    floatx4& acc0, floatx4& acc1)
{
    constexpr int D = (NC < 3) ? NC : 3;
    short8 af[3][8];
    #pragma unroll
    for (int c = 0; c < D; ++c)
        #pragma unroll
        for (int ss = 0; ss < 8; ++ss)
            af[c][ss] = *(const short8*)(pA + (size_t)c * 256 + ss * 32);
    #pragma unroll
    for (int c = 0; c < NC; ++c) {
        #pragma unroll
        for (int ss = 0; ss < 8; ++ss) {
            const int s = (W + c) * 8 + ss;
            short8 bf0 = *(const short8*)&Wlds[s * 1024 + lane * 8];
            short8 bf1 = *(const short8*)&Wlds[s * 1024 + 512 + lane * 8];
            acc0 = __builtin_amdgcn_mfma_f32_16x16x32_bf16(af[c % 3][ss], bf0, acc0, 0, 0, 0);
            acc1 = __builtin_amdgcn_mfma_f32_16x16x32_bf16(af[c % 3][ss], bf1, acc1, 0, 0, 0);
        }
        if (c + 3 < NC) {
            #pragma unroll
            for (int ss = 0; ss < 8; ++ss)
                af[(c + 3) % 3][ss] = *(const short8*)(pA + (size_t)(c + 3) * 256 + ss * 32);
        }
    }
}

// ---------------- diagonal fused LSTM step (fallback path) ----------------
__global__ __launch_bounds__(512) void lstm_diag(
    const __hip_bfloat16* __restrict__ inbf,
    const __hip_bfloat16* __restrict__ Wpack0,
    const __hip_bfloat16* __restrict__ Wpack1,
    const float* __restrict__ b0, const float* __restrict__ b1,
    __hip_bfloat16* __restrict__ h0_cur,
    const __hip_bfloat16* __restrict__ h0_prev,
    float* __restrict__ c0, float* __restrict__ c1,
    __hip_bfloat16* __restrict__ H1all,
    int d)
{
    const int bid = blockIdx.x;
    const int layer = (bid >> 3) & 1;
    const int j = ((bid >> 4) << 3) | (bid & 7);
    if (layer == 0 && d >= T_STEPS) return;
    if (layer == 1 && d == 0) return;

    __shared__ __attribute__((aligned(16))) __hip_bfloat16 Wlds[65536];

    const int tid = threadIdx.x;
    const int wave = tid >> 6, lane = tid & 63;
    const int quad = lane >> 4, l16 = lane & 15;

    const __hip_bfloat16 *A0, *A1;
    int A0stride;
    const float* bb; float* cst; __hip_bfloat16* hout;
    bool first;
    if (layer == 0) {
        first = (d == 0);
        bb = b0; cst = c0;
        A0 = inbf + (size_t)d * (BATCH * VOCAB); A0stride = VOCAB;
        A1 = h0_prev;
        hout = h0_cur;
        const __hip_bfloat16* Wp = Wpack0 + (size_t)j * (NST0 * 1024);
        #pragma unroll
        for (int it = 0; it < 10; ++it)
            load_lds16(Wp + it * 4096 + tid * 8, Wlds + it * 4096 + tid * 8);
    } else {
        first = (d == 1);
        bb = b1; cst = c1;
        A0 = h0_prev; A0stride = NH;
        A1 = (d >= 2) ? (H1all + (size_t)(d - 2) * (BATCH * NH)) : h0_prev;
        hout = H1all + (size_t)(d - 1) * (BATCH * NH);
        const __hip_bfloat16* Wp = Wpack1 + (size_t)j * (NST1 * 1024);
        #pragma unroll
        for (int it = 0; it < 16; ++it)
            load_lds16(Wp + it * 4096 + tid * 8, Wlds + it * 4096 + tid * 8);
    }

    const int row = wave * 16 + l16;
    const __hip_bfloat16* pA0 = A0 + (size_t)row * A0stride + quad * 8;
    const __hip_bfloat16* pA1 = A1 + (size_t)row * NH + quad * 8;

    const int cc = j * 8 + (l16 & 7);
    float bv0 = bb[((l16 < 8) ? 0 : 1) * NH + cc];
    float bv1 = bb[((l16 < 8) ? 2 : 3) * NH + cc];
    float cold[4];
    {
        const int bbase = 16 * wave + quad * 4;
        #pragma unroll
        for (int r = 0; r < 4; ++r)
            cold[r] = first ? 0.f : cst[(size_t)(bbase + r) * NH + cc];
    }
    floatx4 acc0 = {bv0, bv0, bv0, bv0};
    floatx4 acc1 = {bv1, bv1, bv1, bv1};

    __syncthreads();
    if (layer == 0) {
        seg_run<1, 0>(pA0, Wlds, lane, acc0, acc1);
        if (!first) seg_run<4, 1>(pA1, Wlds, lane, acc0, acc1);
    } else {
        if (first) {
            seg_run<4, 0>(pA0, Wlds, lane, acc0, acc1);
        } else {
            seg_run<4, 4>(pA1, Wlds, lane, acc0, acc1);
            seg_run<4, 0>(pA0, Wlds, lane, acc0, acc1);
        }
    }

    #pragma unroll
    for (int r = 0; r < 4; ++r) {
        float a0 = acc0[r], a1 = acc1[r];
        float p0 = __shfl_xor(a0, 8, 64);
        float p1 = __shfl_xor(a1, 8, 64);
        if (l16 < 8) {
            int b = 16 * wave + quad * 4 + r;
            float f  = sigmoidf_(a0);
            float ig = sigmoidf_(p0);
            float oo = sigmoidf_(a1);
            float gg = tanhf_(p1);
            size_t idx = (size_t)b * NH + cc;
            float cn = f * cold[r] + ig * gg;
            float hn = oo * tanhf_(cn);
            cst[idx] = cn;
            hout[idx] = __float2bfloat16(hn);
        }
    }
}

// ---------------- distributed epoch sync (wave-0 poll + s_barrier) ----------
// Arrival: one sc1 store of completed-step count to ep[j]. Wait: wave 0 only
// polls all 128 slots (2 coalesced sc1 lane-loads + __all); other waves park
// at s_barrier -> only 256 pollers chip-wide (not 2048), minimizing L3
// contention with the critical-path h-panel fills.
__device__ __forceinline__ void spin_all_ge(const uint32_t* ep, uint32_t target,
                                            int lane, int wave) {
    asm volatile("" ::: "memory");
    if (wave == 0) {
        for (;;) {
            uint32_t a = __hip_atomic_load(&ep[lane], __ATOMIC_RELAXED, __HIP_MEMORY_SCOPE_AGENT);
            uint32_t b = __hip_atomic_load(&ep[lane + 64], __ATOMIC_RELAXED, __HIP_MEMORY_SCOPE_AGENT);
            if (__all(a >= target && b >= target)) break;
            __builtin_amdgcn_s_sleep(1);
        }
    }
    __builtin_amdgcn_s_barrier();
    asm volatile("" ::: "memory");
}

__device__ __forceinline__ void arrive_ep(uint32_t* slot, uint32_t val) {
    __syncthreads();   // each wave drains vmcnt: sc1 h-stores device-visible
    asm volatile("" ::: "memory");
    if (threadIdx.x == 0)
        __hip_atomic_store(slot, val, __ATOMIC_RELAXED, __HIP_MEMORY_SCOPE_AGENT);
}

__global__ void zero_bar(uint32_t* p) { p[threadIdx.x] = 0; }

// ---- epilogue: gates, c-reg update, pack 8 cols -> 2x8B sc1 stores ----
__device__ __forceinline__ void epilogue_store(
    floatx4 acc0, floatx4 acc1, float* creg, bool first,
    int wave, int quad, int l16, int cc8base,
    __hip_bfloat16* __restrict__ hout)
{
    #pragma unroll
    for (int r = 0; r < 4; ++r) {
        float a0 = acc0[r], a1 = acc1[r];
        float p0 = __shfl_xor(a0, 8, 64);
        float p1 = __shfl_xor(a1, 8, 64);
        float f  = sigmoidf_(a0);
        float ig = sigmoidf_(p0);
        float oo = sigmoidf_(a1);
        float gg = tanhf_(p1);
        float cn = f * (first ? 0.f : creg[r]) + ig * gg;
        if (l16 < 8) creg[r] = cn;
        float hn = oo * tanhf_(cn);
        union { __hip_bfloat16 h; unsigned short u; } cv;
        cv.h = __float2bfloat16(hn);
        unsigned int v1 = (unsigned int)cv.u |
                          (__shfl_xor((unsigned int)cv.u, 1, 64) << 16);
        unsigned int v2 = __shfl_xor(v1, 2, 64);
        unsigned long long p8 = (unsigned long long)v1 |
                                ((unsigned long long)v2 << 32);
        if (l16 == 0 || l16 == 4) {
            int b = 16 * wave + quad * 4 + r;
            __hip_atomic_store((unsigned long long*)&hout[(size_t)b * NH + cc8base + l16],
                               p8, __ATOMIC_RELAXED, __HIP_MEMORY_SCOPE_AGENT);
        }
    }
}

// ---------------- persistent LSTM v8: K-split + conflict-free reduce ----------
// v7 with its two counter-indicted defects removed:
//  (1) reduce-cell index quad*16+l16 (lane-linear 16B) -> zero bank conflicts
//      on both ds_write_b128 and ds_read_b128 (v7's l16*4+quad gave lanes a
//      64B stride within a phase group = 8-way conflict, 2.35e8 cycles).
//  (2) wave-0-only epoch polling + s_barrier release (v7 had all 8 waves
//      polling -> 2048 sc1 load streams hammering the L3 coherent point).
//  (3) depth-2 A-load pipelining across the 4-slice groups (afA/afB).
__global__ __launch_bounds__(512, 2) void lstm_persist8(
    const __hip_bfloat16* __restrict__ inbf,
    const __hip_bfloat16* __restrict__ Wpack0,
    const __hip_bfloat16* __restrict__ Wpack1,
    const float* __restrict__ b0, const float* __restrict__ b1,
    __hip_bfloat16* __restrict__ H0all,        // [256][128][1024]
    __hip_bfloat16* __restrict__ H1all,        // [256][128][1024]
    uint32_t* __restrict__ bar)                // [0..127]=ep0, [128..255]=ep1
{
    __shared__ __attribute__((aligned(16))) float red[32768];   // 128 KB

    const int bid = blockIdx.x;
    const int layer = (bid >> 3) & 1;
    const int j = ((bid >> 4) << 3) | (bid & 7);
    const int tid = threadIdx.x;
    const int wv = tid >> 6, lane = tid & 63;
    const int quad = lane >> 4, l16 = lane & 15;

    uint32_t* ep0 = bar;
    uint32_t* ep1 = bar + 128;

    // ---- one-time: this wave's B-fragments -> registers ----
    short8 breg[8][2];
    if (layer == 0) {
        const __hip_bfloat16* Wp = Wpack0 + (size_t)j * (NST0 * 1024);
        #pragma unroll
        for (int t = 0; t < 2; ++t)
            breg[0][t] = *(const short8*)(Wp + ((size_t)wv * 2 + t) * 512 + lane * 8);
        #pragma unroll
        for (int i = 0; i < 4; ++i) {
            const int ks = 8 + 4 * wv + i;
            #pragma unroll
            for (int t = 0; t < 2; ++t)
                breg[1 + i][t] = *(const short8*)(Wp + ((size_t)ks * 2 + t) * 512 + lane * 8);
        }
        #pragma unroll
        for (int i = 5; i < 8; ++i) {
            breg[i][0] = breg[0][0];
            breg[i][1] = breg[0][1];
        }
    } else {
        const __hip_bfloat16* Wp = Wpack1 + (size_t)j * (NST1 * 1024);
        #pragma unroll
        for (int i = 0; i < 4; ++i) {
            const int ks1 = 32 + 4 * wv + i;      // h1 slice
            const int ks0 = 4 * wv + i;           // h0 slice
            #pragma unroll
            for (int t = 0; t < 2; ++t) {
                breg[i][t]     = *(const short8*)(Wp + ((size_t)ks1 * 2 + t) * 512 + lane * 8);
                breg[4 + i][t] = *(const short8*)(Wp + ((size_t)ks0 * 2 + t) * 512 + lane * 8);
            }
        }
    }

    const int cc = j * 8 + (l16 & 7);
    const float* bb = layer ? b1 : b0;
    const float bv0 = bb[((l16 < 8) ? 0 : 1) * NH + cc];
    const float bv1 = bb[((l16 < 8) ? 2 : 3) * NH + cc];
    float creg[4] = {0.f, 0.f, 0.f, 0.f};

    const int hcol = 4 * wv * 32 + quad * 8;      // h-slice base column (elems)
    const int xcol = wv * 32 + quad * 8;          // L0 x-slice base

    const int dlo = layer ? 1 : 0;
    const int dhi = layer ? T_STEPS : (T_STEPS - 1);

    // load 8 m-fragments of the given slice i into BUF
    #define LOAD_AF(BUF, PBASE, STRIDE, COLBASE, I) do {                         \
        _Pragma("unroll")                                                        \
        for (int m_ = 0; m_ < 8; ++m_)                                           \
            BUF[m_] = *(const short8*)((PBASE) +                                 \
                (size_t)(m_ * 16 + l16) * (STRIDE) + (COLBASE) + (I) * 32);      \
    } while (0)
    // MFMA 8 m-fragments of BUF against breg[WIDX]
    #define MFMA_GRP(BUF, WIDX) do {                                             \
        _Pragma("unroll")                                                        \
        for (int m_ = 0; m_ < 8; ++m_) {                                         \
            acc[m_][0] = __builtin_amdgcn_mfma_f32_16x16x32_bf16(BUF[m_], breg[WIDX][0], acc[m_][0], 0, 0, 0); \
            acc[m_][1] = __builtin_amdgcn_mfma_f32_16x16x32_bf16(BUF[m_], breg[WIDX][1], acc[m_][1], 0, 0, 0); \
        }                                                                        \
    } while (0)

    for (int d = dlo; d <= dhi; ++d) {
        const bool first = (d == dlo);
        floatx4 acc[8][2];
        #pragma unroll
        for (int m = 0; m < 8; ++m) {
            acc[m][0] = (floatx4)0.f;
            acc[m][1] = (floatx4)0.f;
        }

        short8 afA[8], afB[8];
        __hip_bfloat16* hout;
        if (layer == 0) {
            // ---- x slice (no dependency) ----
            const __hip_bfloat16* pX = inbf + (size_t)d * (BATCH * VOCAB);
            LOAD_AF(afA, pX, VOCAB, xcol, 0);
            MFMA_GRP(afA, 0);
            if (!first) {
                spin_all_ge(ep0, (uint32_t)d, lane, wv);
                const __hip_bfloat16* pH0 = H0all + (size_t)(d - 1) * (BATCH * NH);
                LOAD_AF(afA, pH0, NH, hcol, 0);
                LOAD_AF(afB, pH0, NH, hcol, 1);   // depth-2: next group in flight
                MFMA_GRP(afA, 1);
                LOAD_AF(afA, pH0, NH, hcol, 2);
                MFMA_GRP(afB, 2);
                LOAD_AF(afB, pH0, NH, hcol, 3);
                MFMA_GRP(afA, 3);
                MFMA_GRP(afB, 4);
            }
            hout = H0all + (size_t)d * (BATCH * NH);
        } else {
            if (!first) {
                // ---- h1 slice (needs only ep1) ----
                spin_all_ge(ep1, (uint32_t)(d - 1), lane, wv);
                const __hip_bfloat16* pH1 = H1all + (size_t)(d - 2) * (BATCH * NH);
                LOAD_AF(afA, pH1, NH, hcol, 0);
                LOAD_AF(afB, pH1, NH, hcol, 1);
                MFMA_GRP(afA, 0);
                LOAD_AF(afA, pH1, NH, hcol, 2);
                MFMA_GRP(afB, 1);
                LOAD_AF(afB, pH1, NH, hcol, 3);
                MFMA_GRP(afA, 2);
                MFMA_GRP(afB, 3);
            }
            // ---- h0 slice (cross-layer dependency) ----
            spin_all_ge(ep0, (uint32_t)d, lane, wv);
            const __hip_bfloat16* pH0 = H0all + (size_t)(d - 1) * (BATCH * NH);
            LOAD_AF(afA, pH0, NH, hcol, 0);
            LOAD_AF(afB, pH0, NH, hcol, 1);
            MFMA_GRP(afA, 4);
            LOAD_AF(afA, pH0, NH, hcol, 2);
            MFMA_GRP(afB, 5);
            LOAD_AF(afB, pH0, NH, hcol, 3);
            MFMA_GRP(afA, 6);
            MFMA_GRP(afB, 7);
            hout = H1all + (size_t)(d - 1) * (BATCH * NH);
        }

        // ---- write partials: cell = ((wv*2+t)*8+m)*64 + quad*16 + l16 ----
        // per-lane byte addr = tile*1024 + lane*16 -> lane-linear, conflict-free
        #pragma unroll
        for (int m = 0; m < 8; ++m) {
            *(floatx4*)&red[((((wv * 2 + 0) * 8 + m) * 64) + quad * 16 + l16) * 4] = acc[m][0];
            *(floatx4*)&red[((((wv * 2 + 1) * 8 + m) * 64) + quad * 16 + l16) * 4] = acc[m][1];
        }
        __syncthreads();

        // ---- sum 8 partials for this wave's 16 rows (m-tile == wv) ----
        floatx4 s0 = (floatx4)0.f, s1 = (floatx4)0.f;
        #pragma unroll
        for (int w = 0; w < 8; ++w) {
            s0 += *(const floatx4*)&red[((((w * 2 + 0) * 8 + wv) * 64) + quad * 16 + l16) * 4];
            s1 += *(const floatx4*)&red[((((w * 2 + 1) * 8 + wv) * 64) + quad * 16 + l16) * 4];
        }
        s0 += bv0;
        s1 += bv1;

        epilogue_store(s0, s1, creg, first, wv, quad, l16, j * 8, hout);

        // arrive: syncthreads (drains sc1 h-stores; also protects red reuse)
        arrive_ep(layer ? &ep1[j] : &ep0[j], (uint32_t)(layer ? d : d + 1));
    }
    #undef LOAD_AF
    #undef MFMA_GRP
}

extern "C" void kernel_launch(void* const* d_in, const int* in_sizes, int n_in,
                              void* d_out, int out_size, void* d_ws, size_t ws_size,
                              hipStream_t stream)
{
    const float* inputs = (const float*)d_in[0];  // [256,128,256]
    const float* emb    = (const float*)d_in[1];  // [256,512]
    const float* w0     = (const float*)d_in[2];  // [1536,4096]
    const float* b0     = (const float*)d_in[3];  // [4096]
    const float* w1     = (const float*)d_in[4];  // [2048,4096]
    const float* b1     = (const float*)d_in[5];  // [4096]
    const float* outw   = (const float*)d_in[6];  // [1024,256]
    const float* outb   = (const float*)d_in[7];  // [256]
    float* out = (float*)d_out;                   // [32768,256]

    char* ws = (char*)d_ws;
    size_t off = 0;
    auto take = [&](size_t bytes) { char* p = ws + off; off += (bytes + 255) & ~(size_t)255; return p; };
    float* Wcomb = (float*)take((size_t)VOCAB * GDIM * 4);                          // 4 MB
    __hip_bfloat16* Wpack0 = (__hip_bfloat16*)take((size_t)128 * NST0 * 1024 * 2);  // 10 MB
    __hip_bfloat16* Wpack1 = (__hip_bfloat16*)take((size_t)128 * NST1 * 1024 * 2);  // 16 MB
    __hip_bfloat16* outwt  = (__hip_bfloat16*)take((size_t)NH * VOCAB * 2);         // 0.5 MB
    __hip_bfloat16* inbf   = (__hip_bfloat16*)take((size_t)T_STEPS * BATCH * VOCAB * 2); // 16 MB
    __hip_bfloat16* h0pp0  = (__hip_bfloat16*)take((size_t)BATCH * NH * 2);
    __hip_bfloat16* h0pp1  = (__hip_bfloat16*)take((size_t)BATCH * NH * 2);
    float* c0 = (float*)take((size_t)BATCH * NH * 4);
    float* c1 = (float*)take((size_t)BATCH * NH * 4);
    uint32_t* bar = (uint32_t*)take(1024);
    __hip_bfloat16* H1all  = (__hip_bfloat16*)take((size_t)T_STEPS * BATCH * NH * 2); // 64 MB
    __hip_bfloat16* H0all  = (__hip_bfloat16*)take((size_t)T_STEPS * BATCH * NH * 2); // 64 MB
    const bool ws_ok = (off <= ws_size);

    // ---- prep ----
    sgemm_f32<<<dim3(GDIM / BN, VOCAB / BM), 256, 0, stream>>>(
        emb, w0, Wcomb, VOCAB, GDIM, EDIM);
    pack_w2<<<dim3(64, VOCAB / 32), 256, 0, stream>>>(Wcomb, Wpack0, 0, NST0);
    pack_w2<<<dim3(64, NH / 32), 256, 0, stream>>>(w0 + (size_t)EDIM * GDIM, Wpack0, VOCAB, NST0);
    pack_w2<<<dim3(64, NH / 32), 256, 0, stream>>>(w1, Wpack1, 0, NST1);
    pack_w2<<<dim3(64, NH / 32), 256, 0, stream>>>(w1 + (size_t)NH * GDIM, Wpack1, NH, NST1);
    transpose_to_bf16<<<dim3(VOCAB / 32, NH / 32), dim3(32, 8), 0, stream>>>(
        outw, outwt, NH, VOCAB);
    {
        size_t n4 = (size_t)T_STEPS * BATCH * VOCAB / 4;
        convert_to_bf16<<<(int)((n4 + 255) / 256), 256, 0, stream>>>(inputs, inbf, n4);
    }
    zero_bar<<<1, 256, 0, stream>>>(bar);

    // ---- recurrence ----
    bool done = false;
    if (ws_ok) {
        void* args[] = { (void*)&inbf, (void*)&Wpack0, (void*)&Wpack1,
                         (void*)&b0, (void*)&b1,
                         (void*)&H0all, (void*)&H1all, (void*)&bar };
        hipError_t ce = hipLaunchCooperativeKernel(lstm_persist8, dim3(256), dim3(512),
                                                   args, 0u, stream);
        done = (ce == hipSuccess);
    }
    if (!done) {
        for (int d = 0; d <= T_STEPS; ++d) {
            __hip_bfloat16* hcur = (d & 1) ? h0pp1 : h0pp0;
            __hip_bfloat16* hprev = (d & 1) ? h0pp0 : h0pp1;
            lstm_diag<<<256, 512, 0, stream>>>(
                inbf, Wpack0, Wpack1, b0, b1, hcur, hprev, c0, c1, H1all, d);
        }
    }

    // ---- logits = H1 @ out_w + out_b ----
    gemm_bt<<<dim3(VOCAB / 128, (T_STEPS * BATCH) / 128), 256, 0, stream>>>(
        H1all, outwt, outb, out, T_STEPS * BATCH, VOCAB, NH);
}

// Round 12
// 4797.696 us; speedup vs baseline: 1.1294x; 1.0305x over previous
//
#include <hip/hip_runtime.h>
#include <hip/hip_bf16.h>
#include <cstdint>
#include <cstddef>

#define T_STEPS 256
#define BATCH   128
#define VOCAB   256
#define EDIM    512
#define NH      1024
#define GDIM    4096   // 4*NH
#define NST0    40     // layer0 k-steps: 8 (x) + 32 (h)
#define NST1    64     // layer1 k-steps: 32 (h0) + 32 (h1)

typedef __attribute__((ext_vector_type(8))) short short8;
typedef __attribute__((ext_vector_type(4))) float floatx4;

__device__ __forceinline__ float sigmoidf_(float x) { return 1.0f / (1.0f + __expf(-x)); }
__device__ __forceinline__ float tanhf_(float x)    { return 1.0f - 2.0f / (__expf(2.0f * x) + 1.0f); }

typedef __attribute__((address_space(1))) const unsigned int guint;
typedef __attribute__((address_space(3))) unsigned int luint;
__device__ __forceinline__ void load_lds16(const void* g, void* l) {
    __builtin_amdgcn_global_load_lds((guint*)g, (luint*)l, 16, 0, 0);
}

// ---------------- fp32 GEMM (prep only: Wcomb = emb @ W0x) ----------------
#define BM 128
#define BN 128
#define BK 16
__global__ __launch_bounds__(256) void sgemm_f32(
    const float* __restrict__ A, const float* __restrict__ B,
    float* __restrict__ C, int M, int N, int K)
{
    __shared__ float As[BK][BM + 4];
    __shared__ float Bs[BK][BN + 4];
    const int tid = threadIdx.x;
    const int tr = tid >> 4, tc = tid & 15;
    const int bm = blockIdx.y, bn = blockIdx.x;
    const float* Ab = A + (size_t)bm * BM * K;
    float acc[8][8];
    #pragma unroll
    for (int i = 0; i < 8; ++i)
        #pragma unroll
        for (int j = 0; j < 8; ++j) acc[i][j] = 0.f;
    for (int k0 = 0; k0 < K; k0 += BK) {
        #pragma unroll
        for (int l = 0; l < 2; ++l) {
            int idx = tid + l * 256;
            int row = idx >> 2, c4 = idx & 3;
            float4 v = *(const float4*)(Ab + (size_t)row * K + k0 + c4 * 4);
            As[c4 * 4 + 0][row] = v.x; As[c4 * 4 + 1][row] = v.y;
            As[c4 * 4 + 2][row] = v.z; As[c4 * 4 + 3][row] = v.w;
        }
        #pragma unroll
        for (int l = 0; l < 2; ++l) {
            int idx = tid + l * 256;
            int row = idx >> 5, c4 = idx & 31;
            *(float4*)&Bs[row][c4 * 4] = *(const float4*)(B + (size_t)(k0 + row) * N + bn * BN + c4 * 4);
        }
        __syncthreads();
        #pragma unroll
        for (int kk = 0; kk < BK; ++kk) {
            float4 a0 = *(const float4*)&As[kk][tr * 8];
            float4 a1 = *(const float4*)&As[kk][tr * 8 + 4];
            float4 b0 = *(const float4*)&Bs[kk][tc * 8];
            float4 b1 = *(const float4*)&Bs[kk][tc * 8 + 4];
            float av[8] = {a0.x, a0.y, a0.z, a0.w, a1.x, a1.y, a1.z, a1.w};
            float bv[8] = {b0.x, b0.y, b0.z, b0.w, b1.x, b1.y, b1.z, b1.w};
            #pragma unroll
            for (int i = 0; i < 8; ++i)
                #pragma unroll
                for (int j = 0; j < 8; ++j) acc[i][j] += av[i] * bv[j];
        }
        __syncthreads();
    }
    #pragma unroll
    for (int i = 0; i < 8; ++i) {
        size_t row = (size_t)bm * BM + tr * 8 + i;
        #pragma unroll
        for (int j = 0; j < 8; j += 4) {
            int col = bn * BN + tc * 8 + j;
            *(float4*)(C + row * N + col) =
                make_float4(acc[i][j], acc[i][j+1], acc[i][j+2], acc[i][j+3]);
        }
    }
}

// ---------------- transpose + fp32->bf16 ----------------
__global__ __launch_bounds__(256) void transpose_to_bf16(
    const float* __restrict__ src, __hip_bfloat16* __restrict__ dst, int R, int C)
{
    __shared__ float t[32][33];
    int x = blockIdx.x * 32 + threadIdx.x;
    #pragma unroll
    for (int i = 0; i < 4; ++i) {
        int y = blockIdx.y * 32 + threadIdx.y + i * 8;
        t[threadIdx.y + i * 8][threadIdx.x] = src[(size_t)y * C + x];
    }
    __syncthreads();
    int x2 = blockIdx.y * 32 + threadIdx.x;
    #pragma unroll
    for (int i = 0; i < 4; ++i) {
        int y2 = blockIdx.x * 32 + threadIdx.y + i * 8;
        dst[(size_t)y2 * R + x2] = __float2bfloat16(t[threadIdx.x][threadIdx.y + i * 8]);
    }
}

// ------- pack weights: per-(block j, k-step s, n-tile t) 1KB fragments -------
// elem_off = ((((j*NSTEPS + s)*2 + t)*64 + quad*16 + l16)*8 + jj
__global__ __launch_bounds__(256) void pack_w2(
    const float* __restrict__ src, __hip_bfloat16* __restrict__ dst,
    int koff, int NSTEPS)
{
    __shared__ float t[64][33];
    const int tid = threadIdx.x;
    const int xt = blockIdx.x;
    const int kt = blockIdx.y;
    {
        int yl = tid >> 3;
        int x0 = (tid & 7) * 8;
        const float* p = src + (size_t)(kt * 32 + yl) * GDIM + xt * 64 + x0;
        float4 v0 = *(const float4*)p;
        float4 v1 = *(const float4*)(p + 4);
        t[x0 + 0][yl] = v0.x; t[x0 + 1][yl] = v0.y; t[x0 + 2][yl] = v0.z; t[x0 + 3][yl] = v0.w;
        t[x0 + 4][yl] = v1.x; t[x0 + 5][yl] = v1.y; t[x0 + 6][yl] = v1.z; t[x0 + 7][yl] = v1.w;
    }
    __syncthreads();
    {
        int ll = tid >> 2;
        int quad = tid & 3;
        int lincol = xt * 64 + ll;
        int g = lincol >> 10, n = lincol & 1023;
        int j = n >> 3, c = n & 7;
        int tt = g >> 1;
        int l16 = (g & 1) * 8 + c;
        int s = (koff >> 5) + kt;
        __hip_bfloat16 o[8];
        #pragma unroll
        for (int jj = 0; jj < 8; ++jj)
            o[jj] = __float2bfloat16(t[ll][quad * 8 + jj]);
        size_t off = ((((size_t)j * NSTEPS + s) * 2 + tt) * 64 + (size_t)quad * 16 + l16) * 8;
        *(uint4*)(dst + off) = *(const uint4*)o;
    }
}

// ---------------- fp32 -> bf16 convert ----------------
__global__ __launch_bounds__(256) void convert_to_bf16(
    const float* __restrict__ src, __hip_bfloat16* __restrict__ dst, size_t n4)
{
    size_t i = (size_t)blockIdx.x * 256 + threadIdx.x;
    if (i < n4) {
        float4 v = *(const float4*)(src + i * 4);
        __hip_bfloat16 o[4] = {__float2bfloat16(v.x), __float2bfloat16(v.y),
                               __float2bfloat16(v.z), __float2bfloat16(v.w)};
        *(uint2*)(dst + i * 4) = *(uint2*)o;
    }
}

// ---------------- bf16 MFMA GEMM (output layer) ----------------
#define GKP 40
__global__ __launch_bounds__(256) void gemm_bt(
    const __hip_bfloat16* __restrict__ A, const __hip_bfloat16* __restrict__ Bt,
    const float* __restrict__ bias, float* __restrict__ C, int M, int N, int K)
{
    __shared__ __hip_bfloat16 As[128 * GKP];
    __shared__ __hip_bfloat16 Bs[128 * GKP];
    const int tid = threadIdx.x;
    const int wave = tid >> 6, lane = tid & 63;
    const int quad = lane >> 4, l16 = lane & 15;
    const int wm = (wave >> 1) * 64, wn = (wave & 1) * 64;
    const size_t Arow0 = (size_t)blockIdx.y * 128;
    const size_t Brow0 = (size_t)blockIdx.x * 128;
    floatx4 acc[4][4];
    #pragma unroll
    for (int i = 0; i < 4; ++i)
        #pragma unroll
        for (int j = 0; j < 4; ++j) acc[i][j] = (floatx4)0.f;

    for (int k0 = 0; k0 < K; k0 += 32) {
        #pragma unroll
        for (int l = 0; l < 2; ++l) {
            int idx = tid + l * 256;
            int row = idx >> 2, seg = idx & 3;
            *(uint4*)(As + row * GKP + seg * 8) =
                *(const uint4*)(A + (Arow0 + row) * K + k0 + seg * 8);
            *(uint4*)(Bs + row * GKP + seg * 8) =
                *(const uint4*)(Bt + (Brow0 + row) * K + k0 + seg * 8);
        }
        __syncthreads();
        short8 af[4], bf[4];
        #pragma unroll
        for (int i = 0; i < 4; ++i)
            af[i] = *(const short8*)(As + (wm + i * 16 + l16) * GKP + quad * 8);
        #pragma unroll
        for (int j = 0; j < 4; ++j)
            bf[j] = *(const short8*)(Bs + (wn + j * 16 + l16) * GKP + quad * 8);
        #pragma unroll
        for (int i = 0; i < 4; ++i)
            #pragma unroll
            for (int j = 0; j < 4; ++j)
                acc[i][j] = __builtin_amdgcn_mfma_f32_16x16x32_bf16(af[i], bf[j], acc[i][j], 0, 0, 0);
        __syncthreads();
    }
    #pragma unroll
    for (int i = 0; i < 4; ++i)
        #pragma unroll
        for (int j = 0; j < 4; ++j) {
            int col = (int)Brow0 + wn + j * 16 + l16;
            float bv = bias ? bias[col] : 0.f;
            #pragma unroll
            for (int r = 0; r < 4; ++r) {
                size_t row = Arow0 + wm + i * 16 + quad * 4 + r;
                C[row * N + col] = acc[i][j][r] + bv;
            }
        }
}

// ---- single-panel segment: prologue (3 chunks' A-loads) + compute with
// rolling depth-3 prefetch. NC chunks from pA, weight chunks W..W+NC-1.
// 8-col 2-tile format. Static indexing only.
template<int NC, int W>
__device__ __forceinline__ void seg_run(
    const __hip_bfloat16* __restrict__ pA,
    const __hip_bfloat16* Wlds, int lane,
    floatx4& acc0, floatx4& acc1)
{
    constexpr int D = (NC < 3) ? NC : 3;
    short8 af[3][8];
    #pragma unroll
    for (int c = 0; c < D; ++c)
        #pragma unroll
        for (int ss = 0; ss < 8; ++ss)
            af[c][ss] = *(const short8*)(pA + (size_t)c * 256 + ss * 32);
    #pragma unroll
    for (int c = 0; c < NC; ++c) {
        #pragma unroll
        for (int ss = 0; ss < 8; ++ss) {
            const int s = (W + c) * 8 + ss;
            short8 bf0 = *(const short8*)&Wlds[s * 1024 + lane * 8];
            short8 bf1 = *(const short8*)&Wlds[s * 1024 + 512 + lane * 8];
            acc0 = __builtin_amdgcn_mfma_f32_16x16x32_bf16(af[c % 3][ss], bf0, acc0, 0, 0, 0);
            acc1 = __builtin_amdgcn_mfma_f32_16x16x32_bf16(af[c % 3][ss], bf1, acc1, 0, 0, 0);
        }
        if (c + 3 < NC) {
            #pragma unroll
            for (int ss = 0; ss < 8; ++ss)
                af[(c + 3) % 3][ss] = *(const short8*)(pA + (size_t)(c + 3) * 256 + ss * 32);
        }
    }
}

// ---------------- diagonal fused LSTM step (fallback path) ----------------
__global__ __launch_bounds__(512) void lstm_diag(
    const __hip_bfloat16* __restrict__ inbf,
    const __hip_bfloat16* __restrict__ Wpack0,
    const __hip_bfloat16* __restrict__ Wpack1,
    const float* __restrict__ b0, const float* __restrict__ b1,
    __hip_bfloat16* __restrict__ h0_cur,
    const __hip_bfloat16* __restrict__ h0_prev,
    float* __restrict__ c0, float* __restrict__ c1,
    __hip_bfloat16* __restrict__ H1all,
    int d)
{
    const int bid = blockIdx.x;
    const int layer = (bid >> 3) & 1;
    const int j = ((bid >> 4) << 3) | (bid & 7);
    if (layer == 0 && d >= T_STEPS) return;
    if (layer == 1 && d == 0) return;

    __shared__ __attribute__((aligned(16))) __hip_bfloat16 Wlds[65536];

    const int tid = threadIdx.x;
    const int wave = tid >> 6, lane = tid & 63;
    const int quad = lane >> 4, l16 = lane & 15;

    const __hip_bfloat16 *A0, *A1;
    int A0stride;
    const float* bb; float* cst; __hip_bfloat16* hout;
    bool first;
    if (layer == 0) {
        first = (d == 0);
        bb = b0; cst = c0;
        A0 = inbf + (size_t)d * (BATCH * VOCAB); A0stride = VOCAB;
        A1 = h0_prev;
        hout = h0_cur;
        const __hip_bfloat16* Wp = Wpack0 + (size_t)j * (NST0 * 1024);
        #pragma unroll
        for (int it = 0; it < 10; ++it)
            load_lds16(Wp + it * 4096 + tid * 8, Wlds + it * 4096 + tid * 8);
    } else {
        first = (d == 1);
        bb = b1; cst = c1;
        A0 = h0_prev; A0stride = NH;
        A1 = (d >= 2) ? (H1all + (size_t)(d - 2) * (BATCH * NH)) : h0_prev;
        hout = H1all + (size_t)(d - 1) * (BATCH * NH);
        const __hip_bfloat16* Wp = Wpack1 + (size_t)j * (NST1 * 1024);
        #pragma unroll
        for (int it = 0; it < 16; ++it)
            load_lds16(Wp + it * 4096 + tid * 8, Wlds + it * 4096 + tid * 8);
    }

    const int row = wave * 16 + l16;
    const __hip_bfloat16* pA0 = A0 + (size_t)row * A0stride + quad * 8;
    const __hip_bfloat16* pA1 = A1 + (size_t)row * NH + quad * 8;

    const int cc = j * 8 + (l16 & 7);
    float bv0 = bb[((l16 < 8) ? 0 : 1) * NH + cc];
    float bv1 = bb[((l16 < 8) ? 2 : 3) * NH + cc];
    float cold[4];
    {
        const int bbase = 16 * wave + quad * 4;
        #pragma unroll
        for (int r = 0; r < 4; ++r)
            cold[r] = first ? 0.f : cst[(size_t)(bbase + r) * NH + cc];
    }
    floatx4 acc0 = {bv0, bv0, bv0, bv0};
    floatx4 acc1 = {bv1, bv1, bv1, bv1};

    __syncthreads();   // drain weight staging
    if (layer == 0) {
        seg_run<1, 0>(pA0, Wlds, lane, acc0, acc1);
        if (!first) seg_run<4, 1>(pA1, Wlds, lane, acc0, acc1);
    } else {
        if (first) {
            seg_run<4, 0>(pA0, Wlds, lane, acc0, acc1);
        } else {
            seg_run<4, 4>(pA1, Wlds, lane, acc0, acc1);
            seg_run<4, 0>(pA0, Wlds, lane, acc0, acc1);
        }
    }

    #pragma unroll
    for (int r = 0; r < 4; ++r) {
        float a0 = acc0[r], a1 = acc1[r];
        float p0 = __shfl_xor(a0, 8, 64);
        float p1 = __shfl_xor(a1, 8, 64);
        if (l16 < 8) {
            int b = 16 * wave + quad * 4 + r;
            float f  = sigmoidf_(a0);
            float ig = sigmoidf_(p0);
            float oo = sigmoidf_(a1);
            float gg = tanhf_(p1);
            size_t idx = (size_t)b * NH + cc;
            float cn = f * cold[r] + ig * gg;
            float hn = oo * tanhf_(cn);
            cst[idx] = cn;
            hout[idx] = __float2bfloat16(hn);
        }
    }
}

// ---------------- distributed epoch sync (no RMW, no fences) ----------------
// Arrival: one sc1 store of completed-step count to ep[j]. Wait: wave 0
// gathers 128 slots with 2 coalesced agent-scope lane-loads + __all, then
// releases via raw s_barrier (no vmcnt drain -> prefetches stay in flight).
__device__ __forceinline__ void spin_all_ge(const uint32_t* ep, uint32_t target,
                                            int lane, int wave) {
    asm volatile("" ::: "memory");
    if (wave == 0) {
        for (;;) {
            uint32_t a = __hip_atomic_load(&ep[lane], __ATOMIC_RELAXED, __HIP_MEMORY_SCOPE_AGENT);
            uint32_t b = __hip_atomic_load(&ep[lane + 64], __ATOMIC_RELAXED, __HIP_MEMORY_SCOPE_AGENT);
            if (__all(a >= target && b >= target)) break;
            __builtin_amdgcn_s_sleep(1);
        }
    }
    __builtin_amdgcn_s_barrier();
    asm volatile("" ::: "memory");
}

__device__ __forceinline__ void arrive_ep(uint32_t* slot, uint32_t val) {
    __syncthreads();   // each wave drains vmcnt: sc1 h-stores device-visible
    asm volatile("" ::: "memory");
    if (threadIdx.x == 0)
        __hip_atomic_store(slot, val, __ATOMIC_RELAXED, __HIP_MEMORY_SCOPE_AGENT);
}

__global__ void zero_bar(uint32_t* p) { p[threadIdx.x] = 0; }

// ---- epilogue: compute gates, update c-regs, pack 8 cols -> 2x8B sc1 stores ----
__device__ __forceinline__ void epilogue_store(
    floatx4 acc0, floatx4 acc1, float* creg, bool first,
    int wave, int quad, int l16, int cc8base,
    __hip_bfloat16* __restrict__ hout)
{
    #pragma unroll
    for (int r = 0; r < 4; ++r) {
        float a0 = acc0[r], a1 = acc1[r];
        float p0 = __shfl_xor(a0, 8, 64);
        float p1 = __shfl_xor(a1, 8, 64);
        float f  = sigmoidf_(a0);
        float ig = sigmoidf_(p0);
        float oo = sigmoidf_(a1);
        float gg = tanhf_(p1);
        float cn = f * (first ? 0.f : creg[r]) + ig * gg;
        if (l16 < 8) creg[r] = cn;
        float hn = oo * tanhf_(cn);
        union { __hip_bfloat16 h; unsigned short u; } cv;
        cv.h = __float2bfloat16(hn);
        // pack 8 lanes (l16 0..7) -> 2 lanes (l16 0,4) of 8B each
        unsigned int v1 = (unsigned int)cv.u |
                          (__shfl_xor((unsigned int)cv.u, 1, 64) << 16); // cols l16,l16+1 on even l16
        unsigned int v2 = __shfl_xor(v1, 2, 64);                         // cols l16+2,l16+3
        unsigned long long p8 = (unsigned long long)v1 |
                                ((unsigned long long)v2 << 32);          // cols l16..l16+3 on l16 in {0,4}
        if (l16 == 0 || l16 == 4) {
            int b = 16 * wave + quad * 4 + r;
            __hip_atomic_store((unsigned long long*)&hout[(size_t)b * NH + cc8base + l16],
                               p8, __ATOMIC_RELAXED, __HIP_MEMORY_SCOPE_AGENT);
        }
    }
}

// ---------------- persistent LSTM v6 (best measured): layer-decoupled + compute-over-wait ----
// 256 blocks (1/CU), XCD-balanced: layer=(bid>>3)&1, j=((bid>>4)<<3)|(bid&7).
// Weights in LDS once; c-state in registers; h-exchange via write-once sc1
// arrays H0all/H1all (plain consumer loads can't be stale).
// Key ordering: each step's dependency waits are INTERLEAVED with compute --
//  L0: [x-chunk compute] -> spin(ep0>=d) -> [4 h0-chunks]
//  L1: spin(ep1>=d-1) -> [4 h1-chunks] -> spin(ep0>=d) -> [4 h0-chunks]
// so the cross-layer hop (ep0 post + L3 refetch) hides under ~3.5us of MFMA.
// Measured (round 8): 4.66 ms persist, 18.1 us/step — best of 8 sync/structure
// variants tested; residual is the structural per-generation chain
// (serial T=256 x [L1 compute + cross-XCD L3 visibility + 128-block skew]).
__global__ __launch_bounds__(512) void lstm_persist6(
    const __hip_bfloat16* __restrict__ inbf,
    const __hip_bfloat16* __restrict__ Wpack0,
    const __hip_bfloat16* __restrict__ Wpack1,
    const float* __restrict__ b0, const float* __restrict__ b1,
    __hip_bfloat16* __restrict__ H0all,        // [256][128][1024]
    __hip_bfloat16* __restrict__ H1all,        // [256][128][1024]
    uint32_t* __restrict__ bar)                // [0..127]=ep0, [128..255]=ep1
{
    __shared__ __attribute__((aligned(16))) __hip_bfloat16 Wlds[65536]; // 128 KB

    const int bid = blockIdx.x;
    const int layer = (bid >> 3) & 1;
    const int j = ((bid >> 4) << 3) | (bid & 7);
    const int tid = threadIdx.x;
    const int wave = tid >> 6, lane = tid & 63;
    const int quad = lane >> 4, l16 = lane & 15;

    uint32_t* ep0 = bar;
    uint32_t* ep1 = bar + 128;

    // ---- one-time: weights -> LDS ----
    if (layer == 0) {
        const __hip_bfloat16* Wp = Wpack0 + (size_t)j * (NST0 * 1024);
        #pragma unroll
        for (int it = 0; it < 10; ++it)
            load_lds16(Wp + it * 4096 + tid * 8, Wlds + it * 4096 + tid * 8);
    } else {
        const __hip_bfloat16* Wp = Wpack1 + (size_t)j * (NST1 * 1024);
        #pragma unroll
        for (int it = 0; it < 16; ++it)
            load_lds16(Wp + it * 4096 + tid * 8, Wlds + it * 4096 + tid * 8);
    }
    __syncthreads();

    const int cc = j * 8 + (l16 & 7);
    const float* bb = layer ? b1 : b0;
    const float bv0 = bb[((l16 < 8) ? 0 : 1) * NH + cc];
    const float bv1 = bb[((l16 < 8) ? 2 : 3) * NH + cc];
    const int row = wave * 16 + l16;
    float creg[4] = {0.f, 0.f, 0.f, 0.f};

    if (layer == 0) {
        // ---------- layer-0 chain ----------
        for (int d = 0; d < T_STEPS; ++d) {
            const bool first = (d == 0);
            const __hip_bfloat16* pX =
                inbf + (size_t)d * (BATCH * VOCAB) + (size_t)row * VOCAB + quad * 8;
            __hip_bfloat16* hout = H0all + (size_t)d * (BATCH * NH);
            floatx4 acc0 = {bv0, bv0, bv0, bv0};
            floatx4 acc1 = {bv1, bv1, bv1, bv1};
            // x-chunk needs no dependency: compute it BEFORE the epoch wait
            seg_run<1, 0>(pX, Wlds, lane, acc0, acc1);
            if (!first) {
                spin_all_ge(ep0, (uint32_t)d, lane, wave);   // h0[d-1] complete
                const __hip_bfloat16* pH0 =
                    H0all + (size_t)(d - 1) * (BATCH * NH) + (size_t)row * NH + quad * 8;
                seg_run<4, 1>(pH0, Wlds, lane, acc0, acc1);
            }
            epilogue_store(acc0, acc1, creg, first, wave, quad, l16, j * 8, hout);
            arrive_ep(&ep0[j], (uint32_t)(d + 1));
        }
    } else {
        // ---------- layer-1 chain ----------
        for (int d = 1; d <= T_STEPS; ++d) {
            const bool first = (d == 1);
            __hip_bfloat16* hout = H1all + (size_t)(d - 1) * (BATCH * NH);
            floatx4 acc0 = {bv0, bv0, bv0, bv0};
            floatx4 acc1 = {bv1, bv1, bv1, bv1};
            if (!first) {
                // h1 half first: needs only the L1 epoch
                spin_all_ge(ep1, (uint32_t)(d - 1), lane, wave);  // h1[d-2] done
                const __hip_bfloat16* pH1 =
                    H1all + (size_t)(d - 2) * (BATCH * NH) + (size_t)row * NH + quad * 8;
                seg_run<4, 4>(pH1, Wlds, lane, acc0, acc1);
            }
            // cross-layer wait: by now ep0[d] is usually already posted
            spin_all_ge(ep0, (uint32_t)d, lane, wave);            // h0[d-1] done
            const __hip_bfloat16* pH0 =
                H0all + (size_t)(d - 1) * (BATCH * NH) + (size_t)row * NH + quad * 8;
            seg_run<4, 0>(pH0, Wlds, lane, acc0, acc1);
            epilogue_store(acc0, acc1, creg, first, wave, quad, l16, j * 8, hout);
            arrive_ep(&ep1[j], (uint32_t)d);
        }
    }
}

extern "C" void kernel_launch(void* const* d_in, const int* in_sizes, int n_in,
                              void* d_out, int out_size, void* d_ws, size_t ws_size,
                              hipStream_t stream)
{
    const float* inputs = (const float*)d_in[0];  // [256,128,256]
    const float* emb    = (const float*)d_in[1];  // [256,512]
    const float* w0     = (const float*)d_in[2];  // [1536,4096]
    const float* b0     = (const float*)d_in[3];  // [4096]
    const float* w1     = (const float*)d_in[4];  // [2048,4096]
    const float* b1     = (const float*)d_in[5];  // [4096]
    const float* outw   = (const float*)d_in[6];  // [1024,256]
    const float* outb   = (const float*)d_in[7];  // [256]
    float* out = (float*)d_out;                   // [32768,256]

    char* ws = (char*)d_ws;
    size_t off = 0;
    auto take = [&](size_t bytes) { char* p = ws + off; off += (bytes + 255) & ~(size_t)255; return p; };
    float* Wcomb = (float*)take((size_t)VOCAB * GDIM * 4);                          // 4 MB
    __hip_bfloat16* Wpack0 = (__hip_bfloat16*)take((size_t)128 * NST0 * 1024 * 2);  // 10 MB
    __hip_bfloat16* Wpack1 = (__hip_bfloat16*)take((size_t)128 * NST1 * 1024 * 2);  // 16 MB
    __hip_bfloat16* outwt  = (__hip_bfloat16*)take((size_t)NH * VOCAB * 2);         // 0.5 MB
    __hip_bfloat16* inbf   = (__hip_bfloat16*)take((size_t)T_STEPS * BATCH * VOCAB * 2); // 16 MB
    __hip_bfloat16* h0pp0  = (__hip_bfloat16*)take((size_t)BATCH * NH * 2);
    __hip_bfloat16* h0pp1  = (__hip_bfloat16*)take((size_t)BATCH * NH * 2);
    float* c0 = (float*)take((size_t)BATCH * NH * 4);
    float* c1 = (float*)take((size_t)BATCH * NH * 4);
    uint32_t* bar = (uint32_t*)take(1024);
    __hip_bfloat16* H1all  = (__hip_bfloat16*)take((size_t)T_STEPS * BATCH * NH * 2); // 64 MB
    __hip_bfloat16* H0all  = (__hip_bfloat16*)take((size_t)T_STEPS * BATCH * NH * 2); // 64 MB
    const bool ws_ok = (off <= ws_size);

    // ---- prep ----
    sgemm_f32<<<dim3(GDIM / BN, VOCAB / BM), 256, 0, stream>>>(
        emb, w0, Wcomb, VOCAB, GDIM, EDIM);
    pack_w2<<<dim3(64, VOCAB / 32), 256, 0, stream>>>(Wcomb, Wpack0, 0, NST0);
    pack_w2<<<dim3(64, NH / 32), 256, 0, stream>>>(w0 + (size_t)EDIM * GDIM, Wpack0, VOCAB, NST0);
    pack_w2<<<dim3(64, NH / 32), 256, 0, stream>>>(w1, Wpack1, 0, NST1);
    pack_w2<<<dim3(64, NH / 32), 256, 0, stream>>>(w1 + (size_t)NH * GDIM, Wpack1, NH, NST1);
    transpose_to_bf16<<<dim3(VOCAB / 32, NH / 32), dim3(32, 8), 0, stream>>>(
        outw, outwt, NH, VOCAB);
    {
        size_t n4 = (size_t)T_STEPS * BATCH * VOCAB / 4;
        convert_to_bf16<<<(int)((n4 + 255) / 256), 256, 0, stream>>>(inputs, inbf, n4);
    }
    zero_bar<<<1, 256, 0, stream>>>(bar);

    // ---- recurrence ----
    bool done = false;
    if (ws_ok) {
        void* args[] = { (void*)&inbf, (void*)&Wpack0, (void*)&Wpack1,
                         (void*)&b0, (void*)&b1,
                         (void*)&H0all, (void*)&H1all, (void*)&bar };
        hipError_t ce = hipLaunchCooperativeKernel(lstm_persist6, dim3(256), dim3(512),
                                                   args, 0u, stream);
        done = (ce == hipSuccess);
    }
    if (!done) {
        for (int d = 0; d <= T_STEPS; ++d) {
            __hip_bfloat16* hcur = (d & 1) ? h0pp1 : h0pp0;
            __hip_bfloat16* hprev = (d & 1) ? h0pp0 : h0pp1;
            lstm_diag<<<256, 512, 0, stream>>>(
                inbf, Wpack0, Wpack1, b0, b1, hcur, hprev, c0, c1, H1all, d);
        }
    }

    // ---- logits = H1 @ out_w + out_b ----
    gemm_bt<<<dim3(VOCAB / 128, (T_STEPS * BATCH) / 128), 256, 0, stream>>>(
        H1all, outwt, outb, out, T_STEPS * BATCH, VOCAB, NH);
}